// Round 3
// baseline (57.546 us; speedup 1.0000x reference)
//
#include <hip/hip_runtime.h>
#include <math.h>

#define D 64
#define DH 32
#define NPB 128         // nodes per block
#define TPB 256         // threads per block; thread = (g = tid>>2, p = tid&3)
                        // thread handles nodes {2g, 2g+1}, output cols [p*16, p*16+16)

// ---------------------------------------------------------------------------
// Softmax over each row-segment sums to exactly 1, so
//   out[i] = has_edge(i) ? h[i]*(1+peak[i]) + bias : bias
// att_src/att_dst/leaky-relu/segment-softmax cancel analytically.
// ---------------------------------------------------------------------------
__global__ void edge_flag_kernel(const int* __restrict__ row, int* __restrict__ flag, int E) {
    int e = blockIdx.x * blockDim.x + threadIdx.x;
    if (e < E) flag[row[e]] = 1;
}

__device__ __forceinline__ float gelu_exact(float v) {
    return 0.5f * v * (1.0f + erff(v * 0.70710678118654752f));
}

__device__ __forceinline__ void fma4(float4& a, float s, const float4 w) {
    a.x = fmaf(s, w.x, a.x); a.y = fmaf(s, w.y, a.y);
    a.z = fmaf(s, w.z, a.z); a.w = fmaf(s, w.w, a.w);
}

__global__ __launch_bounds__(TPB) void gat_fused3(
    const float* __restrict__ x, const float* __restrict__ Wlin,
    const float* __restrict__ bias, const float* __restrict__ W1,
    const float* __restrict__ b1, const float* __restrict__ W2,
    const float* __restrict__ b2, const int* __restrict__ flag,
    float* __restrict__ out, int N)
{
    __shared__ float sW[D][D];        // 16 KB
    __shared__ float sW1[D][DH];      // 8 KB
    __shared__ float sX[NPB][D + 4];  // 34 KB; reused for h
    __shared__ float sb1[DH], sW2[DH], sbias[D];
    __shared__ float sb2;

    const int tid  = threadIdx.x;
    const int base = blockIdx.x * NPB;

    // ---- stage weights (coalesced float4) ----
    {
        float4* dW = (float4*)&sW[0][0];
        const float4* gW = (const float4*)Wlin;
        for (int idx = tid; idx < D * D / 4; idx += TPB) dW[idx] = gW[idx];
        float4* dW1 = (float4*)&sW1[0][0];
        const float4* gW1 = (const float4*)W1;
        for (int idx = tid; idx < D * DH / 4; idx += TPB) dW1[idx] = gW1[idx];
        if (tid < DH) { sb1[tid] = b1[tid]; sW2[tid] = W2[tid]; }
        if (tid >= 64 && tid < 128) sbias[tid - 64] = bias[tid - 64];
        if (tid == 128) sb2 = b2[0];
    }
    // ---- stage x tile ----
    {
        const float4* gx = (const float4*)(x + (size_t)base * D);
        for (int idx = tid; idx < NPB * (D / 4); idx += TPB) {
            const int r = idx >> 4, c = idx & 15;
            if (base + r < N) *(float4*)&sX[r][c * 4] = gx[idx];
        }
    }
    __syncthreads();

    const int g   = tid >> 2;
    const int p   = tid & 3;
    const int p16 = p * 16;
    const int n0  = 2 * g;           // local node pair

    // ---- h[{n0,n0+1}, p16..p16+16) = x @ W ----
    float4 a00 = make_float4(0.f,0.f,0.f,0.f), a01 = a00, a02 = a00, a03 = a00;
    float4 a10 = a00, a11 = a00, a12 = a00, a13 = a00;
#pragma unroll 2
    for (int k = 0; k < D; k += 4) {
        float xa[4], xb[4];
        { float4 v = *(const float4*)&sX[n0][k];     xa[0]=v.x; xa[1]=v.y; xa[2]=v.z; xa[3]=v.w; }
        { float4 v = *(const float4*)&sX[n0 + 1][k]; xb[0]=v.x; xb[1]=v.y; xb[2]=v.z; xb[3]=v.w; }
#pragma unroll
        for (int u = 0; u < 4; ++u) {
            const float4* wr = (const float4*)&sW[k + u][p16];
            const float4 w0 = wr[0], w1 = wr[1], w2v = wr[2], w3 = wr[3];
            fma4(a00, xa[u], w0); fma4(a01, xa[u], w1);
            fma4(a02, xa[u], w2v); fma4(a03, xa[u], w3);
            fma4(a10, xb[u], w0); fma4(a11, xb[u], w1);
            fma4(a12, xb[u], w2v); fma4(a13, xb[u], w3);
        }
    }
    __syncthreads();   // all x reads done -> safe to overwrite tile with h
    *(float4*)&sX[n0][p16 + 0]      = a00;
    *(float4*)&sX[n0][p16 + 4]      = a01;
    *(float4*)&sX[n0][p16 + 8]      = a02;
    *(float4*)&sX[n0][p16 + 12]     = a03;
    *(float4*)&sX[n0 + 1][p16 + 0]  = a10;
    *(float4*)&sX[n0 + 1][p16 + 4]  = a11;
    *(float4*)&sX[n0 + 1][p16 + 8]  = a12;
    *(float4*)&sX[n0 + 1][p16 + 12] = a13;
    __syncthreads();

    // ---- t[{n0,n0+1}, p*8..p*8+8) = h @ W1 + b1 ----
    float4 t00 = ((const float4*)sb1)[p * 2 + 0];
    float4 t01 = ((const float4*)sb1)[p * 2 + 1];
    float4 t10 = t00, t11 = t01;
#pragma unroll 2
    for (int k = 0; k < D; k += 4) {
        float ha[4], hb[4];
        { float4 v = *(const float4*)&sX[n0][k];     ha[0]=v.x; ha[1]=v.y; ha[2]=v.z; ha[3]=v.w; }
        { float4 v = *(const float4*)&sX[n0 + 1][k]; hb[0]=v.x; hb[1]=v.y; hb[2]=v.z; hb[3]=v.w; }
#pragma unroll
        for (int u = 0; u < 4; ++u) {
            const float4* wr = (const float4*)&sW1[k + u][p * 8];
            const float4 w0 = wr[0], w1 = wr[1];
            fma4(t00, ha[u], w0); fma4(t01, ha[u], w1);
            fma4(t10, hb[u], w0); fma4(t11, hb[u], w1);
        }
    }

    // ---- peak partial dot (8 cols each) + 4-lane butterfly ----
    const float4 u0 = ((const float4*)sW2)[p * 2 + 0];
    const float4 u1 = ((const float4*)sW2)[p * 2 + 1];
    float pp0 = 0.f, pp1 = 0.f;
    pp0 = fmaf(gelu_exact(t00.x), u0.x, pp0); pp0 = fmaf(gelu_exact(t00.y), u0.y, pp0);
    pp0 = fmaf(gelu_exact(t00.z), u0.z, pp0); pp0 = fmaf(gelu_exact(t00.w), u0.w, pp0);
    pp0 = fmaf(gelu_exact(t01.x), u1.x, pp0); pp0 = fmaf(gelu_exact(t01.y), u1.y, pp0);
    pp0 = fmaf(gelu_exact(t01.z), u1.z, pp0); pp0 = fmaf(gelu_exact(t01.w), u1.w, pp0);
    pp1 = fmaf(gelu_exact(t10.x), u0.x, pp1); pp1 = fmaf(gelu_exact(t10.y), u0.y, pp1);
    pp1 = fmaf(gelu_exact(t10.z), u0.z, pp1); pp1 = fmaf(gelu_exact(t10.w), u0.w, pp1);
    pp1 = fmaf(gelu_exact(t11.x), u1.x, pp1); pp1 = fmaf(gelu_exact(t11.y), u1.y, pp1);
    pp1 = fmaf(gelu_exact(t11.z), u1.z, pp1); pp1 = fmaf(gelu_exact(t11.w), u1.w, pp1);
    pp0 += __shfl_xor(pp0, 1); pp0 += __shfl_xor(pp0, 2);
    pp1 += __shfl_xor(pp1, 1); pp1 += __shfl_xor(pp1, 2);

    const int gn0 = base + n0;
    const bool v0 = gn0 < N, v1 = (gn0 + 1) < N;
    float s0 = 0.f, s1 = 0.f;
    if (v0 && flag[gn0] != 0)     s0 = 1.f + 1.f / (1.f + expf(-(pp0 + sb2)));
    if (v1 && flag[gn0 + 1] != 0) s1 = 1.f + 1.f / (1.f + expf(-(pp1 + sb2)));

    // ---- out = h*scale + bias ----
    const float4* bv = (const float4*)&sbias[p16];
    const float4 b0 = bv[0], b1v = bv[1], b2v = bv[2], b3v = bv[3];
    if (v0) {
        float4* outr = (float4*)(out + (size_t)gn0 * D + p16);
        float4 o0 = b0, o1 = b1v, o2 = b2v, o3 = b3v;
        fma4(o0, s0, a00); fma4(o1, s0, a01); fma4(o2, s0, a02); fma4(o3, s0, a03);
        outr[0] = o0; outr[1] = o1; outr[2] = o2; outr[3] = o3;
    }
    if (v1) {
        float4* outr = (float4*)(out + (size_t)(gn0 + 1) * D + p16);
        float4 o0 = b0, o1 = b1v, o2 = b2v, o3 = b3v;
        fma4(o0, s1, a10); fma4(o1, s1, a11); fma4(o2, s1, a12); fma4(o3, s1, a13);
        outr[0] = o0; outr[1] = o1; outr[2] = o2; outr[3] = o3;
    }
}

extern "C" void kernel_launch(void* const* d_in, const int* in_sizes, int n_in,
                              void* d_out, int out_size, void* d_ws, size_t ws_size,
                              hipStream_t stream) {
    const float* x    = (const float*)d_in[0];
    const int*   eidx = (const int*)d_in[1];   // [2, E]: first E entries = row
    const float* Wlin = (const float*)d_in[2];
    // d_in[3] att_src, d_in[4] att_dst cancel (segment softmax sums to 1)
    const float* bias = (const float*)d_in[5];
    const float* W1   = (const float*)d_in[6];
    const float* b1   = (const float*)d_in[7];
    const float* W2   = (const float*)d_in[8];
    const float* b2   = (const float*)d_in[9];
    float* out = (float*)d_out;

    const int N = in_sizes[0] / D;
    const int E = in_sizes[1] / 2;

    int* flag = (int*)d_ws;
    hipMemsetAsync(flag, 0, (size_t)N * sizeof(int), stream);
    edge_flag_kernel<<<(E + 255) / 256, 256, 0, stream>>>(eidx, flag, E);
    gat_fused3<<<(N + NPB - 1) / NPB, TPB, 0, stream>>>(x, Wlin, bias, W1, b1, W2, b2,
                                                        flag, out, N);
}

// Round 4
// 39.811 us; speedup vs baseline: 1.4455x; 1.4455x over previous
//
#include <hip/hip_runtime.h>
#include <math.h>

#define D 64
#define DH 32

typedef __attribute__((ext_vector_type(8))) short bf16x8;   // MFMA A/B frag (4 VGPRs)
typedef __attribute__((ext_vector_type(4))) float f32x4;    // MFMA C/D frag

// fp32 -> bf16 RNE (finite inputs)
static __device__ __forceinline__ unsigned short f2b(float f) {
    unsigned int u = __builtin_bit_cast(unsigned int, f);
    u += 0x7FFFu + ((u >> 16) & 1u);
    return (unsigned short)(u >> 16);
}
static __device__ __forceinline__ float b2f(unsigned short s) {
    unsigned int u = ((unsigned int)s) << 16;
    return __builtin_bit_cast(float, u);
}
static __device__ __forceinline__ float gelu_exact(float v) {
    return 0.5f * v * (1.0f + erff(v * 0.70710678118654752f));
}

// ---------------------------------------------------------------------------
// Softmax over each row-segment sums to exactly 1, so
//   out[i] = has_edge(i) ? h[i]*(1+peak[i]) + bias : bias
// ---------------------------------------------------------------------------
__global__ void edge_flag_kernel(const int* __restrict__ row, int* __restrict__ flag, int E) {
    int i4 = (blockIdx.x * blockDim.x + threadIdx.x) * 4;
    if (i4 + 3 < E) {
        int4 r = *(const int4*)(row + i4);
        flag[r.x] = 1; flag[r.y] = 1; flag[r.z] = 1; flag[r.w] = 1;
    } else if (i4 < E) {
        for (int j = i4; j < E; ++j) flag[row[j]] = 1;
    }
}

// 128 threads = 2 waves; each wave owns 32 nodes (2 MFMA M-tiles).
// GEMM1: h = x @ W_lin via mfma_f32_16x16x32_bf16 (A from global, B from LDS W^T).
// h -> per-wave swizzled LDS (bf16) -> GEMM2: t = h @ W1 -> peak -> epilogue.
__global__ __launch_bounds__(128) void gat_mfma(
    const float* __restrict__ x, const float* __restrict__ Wlin,
    const float* __restrict__ bias, const float* __restrict__ W1,
    const float* __restrict__ b1, const float* __restrict__ W2,
    const float* __restrict__ b2, const int* __restrict__ flag,
    float* __restrict__ out, int N)
{
    __shared__ unsigned short sWT[D][D];     // W_lin^T bf16, XOR-swizzled rows (8 KB)
    __shared__ unsigned short sW1T[DH][D];   // W1^T bf16, swizzled (4 KB)
    __shared__ unsigned short sH[2][32][D];  // per-wave h bf16, swizzled (8 KB)
    __shared__ float sScale[2][32];

    const int tid = threadIdx.x;

    // ---- stage W^T / W1^T in bf16 with swizzle (once per block) ----
    {
        const float4* gW = (const float4*)Wlin;   // W[k][n], 1024 float4
#pragma unroll
        for (int it = 0; it < 8; ++it) {
            const int idx = tid + 128 * it;
            const float4 v = gW[idx];
            const int k = idx >> 4, n0 = (idx & 15) * 4;
            sWT[n0 + 0][k ^ (((n0 + 0) & 7) << 3)] = f2b(v.x);
            sWT[n0 + 1][k ^ (((n0 + 1) & 7) << 3)] = f2b(v.y);
            sWT[n0 + 2][k ^ (((n0 + 2) & 7) << 3)] = f2b(v.z);
            sWT[n0 + 3][k ^ (((n0 + 3) & 7) << 3)] = f2b(v.w);
        }
        const float4* gW1 = (const float4*)W1;    // W1[k][n], 512 float4
#pragma unroll
        for (int it = 0; it < 4; ++it) {
            const int idx = tid + 128 * it;
            const float4 v = gW1[idx];
            const int k = idx >> 3, n0 = (idx & 7) * 4;
            sW1T[n0 + 0][k ^ (((n0 + 0) & 7) << 3)] = f2b(v.x);
            sW1T[n0 + 1][k ^ (((n0 + 1) & 7) << 3)] = f2b(v.y);
            sW1T[n0 + 2][k ^ (((n0 + 2) & 7) << 3)] = f2b(v.z);
            sW1T[n0 + 3][k ^ (((n0 + 3) & 7) << 3)] = f2b(v.w);
        }
    }
    __syncthreads();

    const int wv   = tid >> 6;       // wave 0/1
    const int lane = tid & 63;
    const int q    = lane >> 4;      // k-group
    const int m    = lane & 15;      // row/col within tile
    const int nodeBase = blockIdx.x * 64 + wv * 32;

    // ---- B-fragments from LDS (held in regs for whole GEMM) ----
    bf16x8 bw[4][2], bw1[2][2];
#pragma unroll
    for (int nt = 0; nt < 4; ++nt)
#pragma unroll
        for (int ks = 0; ks < 2; ++ks) {
            const int n = nt * 16 + m;
            bw[nt][ks] = *(const bf16x8*)&sWT[n][(ks * 32 + q * 8) ^ ((n & 7) << 3)];
        }
#pragma unroll
    for (int nt = 0; nt < 2; ++nt)
#pragma unroll
        for (int ks = 0; ks < 2; ++ks) {
            const int n = nt * 16 + m;
            bw1[nt][ks] = *(const bf16x8*)&sW1T[n][(ks * 32 + q * 8) ^ ((n & 7) << 3)];
        }

    // ---- A-fragments of x straight from global (lane: row m, 8 k at q*8) ----
    bf16x8 ax[2][2];
#pragma unroll
    for (int mt = 0; mt < 2; ++mt)
#pragma unroll
        for (int ks = 0; ks < 2; ++ks) {
            int r = nodeBase + mt * 16 + m;
            if (r > N - 1) r = N - 1;
            const float* px = x + (size_t)r * D + ks * 32 + q * 8;
            const float4 u0 = *(const float4*)px;
            const float4 u1 = *(const float4*)(px + 4);
            bf16x8 a;
            a[0] = (short)f2b(u0.x); a[1] = (short)f2b(u0.y);
            a[2] = (short)f2b(u0.z); a[3] = (short)f2b(u0.w);
            a[4] = (short)f2b(u1.x); a[5] = (short)f2b(u1.y);
            a[6] = (short)f2b(u1.z); a[7] = (short)f2b(u1.w);
            ax[mt][ks] = a;
        }

    // ---- GEMM1: h = x @ W_lin ----
    f32x4 acc1[2][4];
#pragma unroll
    for (int mt = 0; mt < 2; ++mt)
#pragma unroll
        for (int nt = 0; nt < 4; ++nt)
            acc1[mt][nt] = (f32x4){0.f, 0.f, 0.f, 0.f};
#pragma unroll
    for (int ks = 0; ks < 2; ++ks)
#pragma unroll
        for (int mt = 0; mt < 2; ++mt)
#pragma unroll
            for (int nt = 0; nt < 4; ++nt)
                acc1[mt][nt] = __builtin_amdgcn_mfma_f32_16x16x32_bf16(
                    ax[mt][ks], bw[nt][ks], acc1[mt][nt], 0, 0, 0);

    // ---- write h to per-wave swizzled LDS (D-layout: row=q*4+r, col=m) ----
#pragma unroll
    for (int mt = 0; mt < 2; ++mt)
#pragma unroll
        for (int nt = 0; nt < 4; ++nt)
#pragma unroll
            for (int r = 0; r < 4; ++r) {
                const int row = mt * 16 + q * 4 + r;
                const int col = nt * 16 + m;
                sH[wv][row][col ^ ((row & 7) << 3)] = f2b(acc1[mt][nt][r]);
            }

    // ---- GEMM2: t = h @ W1 + b1 ----
    const float b1v0 = b1[m], b1v1 = b1[m + 16];
    f32x4 acc2[2][2];
#pragma unroll
    for (int mt = 0; mt < 2; ++mt) {
        acc2[mt][0] = (f32x4){b1v0, b1v0, b1v0, b1v0};
        acc2[mt][1] = (f32x4){b1v1, b1v1, b1v1, b1v1};
    }
    bf16x8 a2[2][2];
#pragma unroll
    for (int mt = 0; mt < 2; ++mt)
#pragma unroll
        for (int ks = 0; ks < 2; ++ks) {
            const int row = mt * 16 + m;
            a2[mt][ks] = *(const bf16x8*)&sH[wv][row][(ks * 32 + q * 8) ^ ((row & 7) << 3)];
        }
#pragma unroll
    for (int ks = 0; ks < 2; ++ks)
#pragma unroll
        for (int mt = 0; mt < 2; ++mt)
#pragma unroll
            for (int nt = 0; nt < 2; ++nt)
                acc2[mt][nt] = __builtin_amdgcn_mfma_f32_16x16x32_bf16(
                    a2[mt][ks], bw1[nt][ks], acc2[mt][nt], 0, 0, 0);

    // ---- peak: pp[n] = sum_c gelu(t[n][c]) * W2[c]; reduce over 16 lanes ----
    const float w2v0 = W2[m], w2v1 = W2[m + 16];
    const float b2s  = b2[0];
    float pv[2][4];
#pragma unroll
    for (int mt = 0; mt < 2; ++mt)
#pragma unroll
        for (int r = 0; r < 4; ++r) {
            float p = gelu_exact(acc2[mt][0][r]) * w2v0
                    + gelu_exact(acc2[mt][1][r]) * w2v1;
            p += __shfl_xor(p, 1);
            p += __shfl_xor(p, 2);
            p += __shfl_xor(p, 4);
            p += __shfl_xor(p, 8);
            pv[mt][r] = p;
        }

    // ---- scale = flag ? 1 + sigmoid(pp + b2) : 0 ; write to sScale ----
#pragma unroll
    for (int mt = 0; mt < 2; ++mt)
#pragma unroll
        for (int r = 0; r < 4; ++r) {
            const int row = mt * 16 + q * 4 + r;
            int g = nodeBase + row;
            if (g > N - 1) g = N - 1;
            const int fl = flag[g];
            const float sc = fl ? (1.f + 1.f / (1.f + expf(-(pv[mt][r] + b2s)))) : 0.f;
            sScale[wv][row] = sc;   // 16 lanes write same value to same addr
        }

    // ---- epilogue: out[row][col] = h*scale + bias, one 256B row per instr ----
    const float bias_l = bias[lane];
    float bias_perm[8];
#pragma unroll
    for (int ri = 0; ri < 8; ++ri) bias_perm[ri] = __shfl_xor(bias_l, ri << 3);

#pragma unroll
    for (int ro = 0; ro < 4; ++ro)
#pragma unroll
        for (int ri = 0; ri < 8; ++ri) {
            const int row = ro * 8 + ri;          // row & 7 == ri
            const int g   = nodeBase + row;
            if (g < N) {
                const float s    = sScale[wv][row];
                const float hval = b2f(sH[wv][row][lane]);    // holds col = lane ^ (ri<<3)
                const int   col  = lane ^ (ri << 3);
                out[(size_t)g * D + col] = fmaf(hval, s, bias_perm[ri]);
            }
        }
}

extern "C" void kernel_launch(void* const* d_in, const int* in_sizes, int n_in,
                              void* d_out, int out_size, void* d_ws, size_t ws_size,
                              hipStream_t stream) {
    const float* x    = (const float*)d_in[0];
    const int*   eidx = (const int*)d_in[1];   // [2, E]: first E entries = row
    const float* Wlin = (const float*)d_in[2];
    // d_in[3] att_src, d_in[4] att_dst cancel (segment softmax sums to 1)
    const float* bias = (const float*)d_in[5];
    const float* W1   = (const float*)d_in[6];
    const float* b1   = (const float*)d_in[7];
    const float* W2   = (const float*)d_in[8];
    const float* b2   = (const float*)d_in[9];
    float* out = (float*)d_out;

    const int N = in_sizes[0] / D;
    const int E = in_sizes[1] / 2;

    int* flag = (int*)d_ws;
    hipMemsetAsync(flag, 0, (size_t)N * sizeof(int), stream);
    edge_flag_kernel<<<(E / 4 + 256) / 256, 256, 0, stream>>>(eidx, flag, E);
    gat_mfma<<<(N + 63) / 64, 128, 0, stream>>>(x, Wlin, bias, W1, b1, W2, b2,
                                                flag, out, N);
}

// Round 5
// 35.890 us; speedup vs baseline: 1.6034x; 1.1093x over previous
//
#include <hip/hip_runtime.h>
#include <math.h>

#define D 64
#define DH 32

typedef __attribute__((ext_vector_type(8))) short bf16x8;   // MFMA A/B frag (4 VGPRs)
typedef __attribute__((ext_vector_type(4))) float f32x4;    // MFMA C/D frag

// fp32 -> bf16 RNE
static __device__ __forceinline__ unsigned short f2b(float f) {
    unsigned int u = __builtin_bit_cast(unsigned int, f);
    u += 0x7FFFu + ((u >> 16) & 1u);
    return (unsigned short)(u >> 16);
}
static __device__ __forceinline__ unsigned int pack_b2(float a, float b) {
    return (unsigned int)f2b(a) | ((unsigned int)f2b(b) << 16);
}
static __device__ __forceinline__ float gelu_exact(float v) {
    return 0.5f * v * (1.0f + erff(v * 0.70710678118654752f));
}

// ---------------------------------------------------------------------------
// Softmax over each row-segment sums to exactly 1, so
//   out[i] = has_edge(i) ? h[i]*(1+peak[i]) + bias : bias
// ---------------------------------------------------------------------------
__global__ void edge_flag_kernel(const int* __restrict__ row, int* __restrict__ flag, int E) {
    int i4 = (blockIdx.x * blockDim.x + threadIdx.x) * 4;
    if (i4 + 3 < E) {
        int4 r = *(const int4*)(row + i4);
        flag[r.x] = 1; flag[r.y] = 1; flag[r.z] = 1; flag[r.w] = 1;
    } else if (i4 < E) {
        for (int j = i4; j < E; ++j) flag[row[j]] = 1;
    }
}

// ---------------------------------------------------------------------------
// Prep: grid-stride zero of flag + (block 0) pack per-lane MFMA fragments:
//  packAW : A-frags of W_lin^T  -> 8 frags (nt*2+ks) x 64 lanes x 16B
//  packAW1: A-frags of W1^T     -> 4 frags (ntW*2+ks) x 64 lanes x 16B
//  packBias[nt][lane] f32x4 = bias[16nt+4q+r];  packB1/packW2 same for b1/W2
// ---------------------------------------------------------------------------
__global__ void prep_kernel(const float* __restrict__ Wlin, const float* __restrict__ W1,
                            const float* __restrict__ bias, const float* __restrict__ b1,
                            const float* __restrict__ W2,
                            int* __restrict__ flag, unsigned short* __restrict__ packAW,
                            unsigned short* __restrict__ packAW1, float* __restrict__ packBias,
                            float* __restrict__ packB1, float* __restrict__ packW2, int N)
{
    const int idx = blockIdx.x * blockDim.x + threadIdx.x;
    const int stride = gridDim.x * blockDim.x;
    for (int i = idx; i < N; i += stride) flag[i] = 0;

    if (blockIdx.x == 0) {
        const int lane = threadIdx.x & 63, part = threadIdx.x >> 6;  // 4 parts
        const int q = lane >> 4, m = lane & 15;
#pragma unroll
        for (int fo = 0; fo < 2; ++fo) {                 // packAW: frags 2*part, 2*part+1
            const int f = part * 2 + fo, nt = f >> 1, ks = f & 1;
#pragma unroll
            for (int j = 0; j < 8; ++j) {
                const int k = 32 * ks + 8 * q + j, n = 16 * nt + m;
                packAW[(f * 64 + lane) * 8 + j] = f2b(Wlin[k * D + n]);
            }
        }
        {                                                 // packAW1: frag = part
            const int f = part, ntW = f >> 1, ks = f & 1;
#pragma unroll
            for (int j = 0; j < 8; ++j) {
                const int k = 32 * ks + 8 * q + j, n = 16 * ntW + m;
                packAW1[(f * 64 + lane) * 8 + j] = f2b(W1[k * DH + n]);
            }
        }
#pragma unroll
        for (int r = 0; r < 4; ++r)                       // packBias: nt = part
            packBias[(part * 64 + lane) * 4 + r] = bias[16 * part + 4 * q + r];
        if (part < 2) {
#pragma unroll
            for (int r = 0; r < 4; ++r)
                packB1[(part * 64 + lane) * 4 + r] = b1[16 * part + 4 * q + r];
        } else {
#pragma unroll
            for (int r = 0; r < 4; ++r)
                packW2[((part - 2) * 64 + lane) * 4 + r] = W2[16 * (part - 2) + 4 * q + r];
        }
    }
}

// ---------------------------------------------------------------------------
// Main: 256 threads = 4 waves, 32 nodes/wave (2 N-tiles of 16), no barriers.
// GEMM1 (h^T = W^T @ x^T): A-frags pre-packed, B-frags of x straight from global.
// h -> per-wave bf16 LDS tile [node][hcol] (b64 writes, b128 frag reads) ->
// GEMM2 (t^T = W1^T @ h^T) -> gelu/W2 dot + shfl reduce -> scale -> epilogue.
// ---------------------------------------------------------------------------
__global__ __launch_bounds__(256) void gat_mfma2(
    const float* __restrict__ x, const int* __restrict__ flag,
    const unsigned short* __restrict__ packAW, const unsigned short* __restrict__ packAW1,
    const float* __restrict__ packBias, const float* __restrict__ packB1,
    const float* __restrict__ packW2, const float* __restrict__ b2,
    float* __restrict__ out, int N)
{
    __shared__ unsigned short sH[4][32][72];   // per-wave h bf16 [node_loc][hcol], 18 KB

    const int tid  = threadIdx.x;
    const int wv   = tid >> 6;
    const int lane = tid & 63;
    const int q    = lane >> 4;
    const int m    = lane & 15;
    const int nodeBase = blockIdx.x * 128 + wv * 32;

    // ---- x B-frags (x^T): lane supplies node=nodeBase+16mt+m, k=32ks+8q+j ----
    bf16x8 bx[2][2];
#pragma unroll
    for (int mt = 0; mt < 2; ++mt) {
        int r = nodeBase + 16 * mt + m; if (r > N - 1) r = N - 1;
        const float* px = x + (size_t)r * D + 8 * q;
#pragma unroll
        for (int ks = 0; ks < 2; ++ks) {
            const float4 u0 = *(const float4*)(px + 32 * ks);
            const float4 u1 = *(const float4*)(px + 32 * ks + 4);
            bf16x8 a;
            a[0] = (short)f2b(u0.x); a[1] = (short)f2b(u0.y);
            a[2] = (short)f2b(u0.z); a[3] = (short)f2b(u0.w);
            a[4] = (short)f2b(u1.x); a[5] = (short)f2b(u1.y);
            a[6] = (short)f2b(u1.z); a[7] = (short)f2b(u1.w);
            bx[mt][ks] = a;
        }
    }

    // ---- W^T A-frags from pre-packed global (L2-hot, coalesced) ----
    bf16x8 aw[4][2];
#pragma unroll
    for (int nt = 0; nt < 4; ++nt)
#pragma unroll
        for (int ks = 0; ks < 2; ++ks)
            aw[nt][ks] = ((const bf16x8*)packAW)[(nt * 2 + ks) * 64 + lane];

    // ---- GEMM1: h^T ----
    f32x4 accH[2][4];
#pragma unroll
    for (int mt = 0; mt < 2; ++mt)
#pragma unroll
        for (int nt = 0; nt < 4; ++nt)
            accH[mt][nt] = (f32x4){0.f, 0.f, 0.f, 0.f};
#pragma unroll
    for (int ks = 0; ks < 2; ++ks)
#pragma unroll
        for (int mt = 0; mt < 2; ++mt)
#pragma unroll
            for (int nt = 0; nt < 4; ++nt)
                accH[mt][nt] = __builtin_amdgcn_mfma_f32_16x16x32_bf16(
                    aw[nt][ks], bx[mt][ks], accH[mt][nt], 0, 0, 0);
    // lane now holds h[node=nodeBase+16mt+m][hcol=16nt+4q+r]

    // ---- h -> per-wave LDS (bf16, b64 writes), then b128 frag reads ----
#pragma unroll
    for (int mt = 0; mt < 2; ++mt)
#pragma unroll
        for (int nt = 0; nt < 4; ++nt) {
            uint2 pk;
            pk.x = pack_b2(accH[mt][nt][0], accH[mt][nt][1]);
            pk.y = pack_b2(accH[mt][nt][2], accH[mt][nt][3]);
            *(uint2*)&sH[wv][16 * mt + m][16 * nt + 4 * q] = pk;
        }
    bf16x8 a2[2][2];
#pragma unroll
    for (int mt = 0; mt < 2; ++mt)
#pragma unroll
        for (int ks = 0; ks < 2; ++ks)
            a2[mt][ks] = *(const bf16x8*)&sH[wv][16 * mt + m][32 * ks + 8 * q];

    // ---- GEMM2: t^T = W1^T @ h^T ----
    bf16x8 aw1[2][2];
#pragma unroll
    for (int nt = 0; nt < 2; ++nt)
#pragma unroll
        for (int ks = 0; ks < 2; ++ks)
            aw1[nt][ks] = ((const bf16x8*)packAW1)[(nt * 2 + ks) * 64 + lane];
    f32x4 b1v0 = ((const f32x4*)packB1)[0 * 64 + lane];
    f32x4 b1v1 = ((const f32x4*)packB1)[1 * 64 + lane];
    f32x4 acc2[2][2];   // [ntW][mt]
    acc2[0][0] = b1v0; acc2[0][1] = b1v0;
    acc2[1][0] = b1v1; acc2[1][1] = b1v1;
#pragma unroll
    for (int ks = 0; ks < 2; ++ks)
#pragma unroll
        for (int nt = 0; nt < 2; ++nt)
#pragma unroll
            for (int mt = 0; mt < 2; ++mt)
                acc2[nt][mt] = __builtin_amdgcn_mfma_f32_16x16x32_bf16(
                    aw1[nt][ks], a2[mt][ks], acc2[nt][mt], 0, 0, 0);
    // lane holds t[node=nodeBase+16mt+m][w1col=16ntW+4q+r]

    // ---- peak: pp = sum gelu(t)*W2, reduce over the 4 q-groups ----
    const f32x4 w2v0 = ((const f32x4*)packW2)[0 * 64 + lane];
    const f32x4 w2v1 = ((const f32x4*)packW2)[1 * 64 + lane];
    const float b2s  = b2[0];
    float scale[2];
#pragma unroll
    for (int mt = 0; mt < 2; ++mt) {
        float pp = 0.f;
#pragma unroll
        for (int r = 0; r < 4; ++r) {
            pp = fmaf(gelu_exact(acc2[0][mt][r]), w2v0[r], pp);
            pp = fmaf(gelu_exact(acc2[1][mt][r]), w2v1[r], pp);
        }
        pp += __shfl_xor(pp, 16);
        pp += __shfl_xor(pp, 32);
        int g = nodeBase + 16 * mt + m;
        const bool v = g < N; if (!v) g = N - 1;
        scale[mt] = (v && flag[g] != 0) ? (1.f + 1.f / (1.f + expf(-(pp + b2s)))) : 0.f;
    }

    // ---- epilogue: out[node][16nt+4q+r] = h*scale + bias ----
    f32x4 biasv[4];
#pragma unroll
    for (int nt = 0; nt < 4; ++nt) biasv[nt] = ((const f32x4*)packBias)[nt * 64 + lane];
#pragma unroll
    for (int mt = 0; mt < 2; ++mt) {
        const int g = nodeBase + 16 * mt + m;
        if (g < N) {
            float* po = out + (size_t)g * D + 4 * q;
#pragma unroll
            for (int nt = 0; nt < 4; ++nt) {
                f32x4 o;
#pragma unroll
                for (int r = 0; r < 4; ++r)
                    o[r] = fmaf(accH[mt][nt][r], scale[mt], biasv[nt][r]);
                *(f32x4*)(po + 16 * nt) = o;
            }
        }
    }
}

extern "C" void kernel_launch(void* const* d_in, const int* in_sizes, int n_in,
                              void* d_out, int out_size, void* d_ws, size_t ws_size,
                              hipStream_t stream) {
    const float* x    = (const float*)d_in[0];
    const int*   eidx = (const int*)d_in[1];   // [2, E]: first E entries = row
    const float* Wlin = (const float*)d_in[2];
    // d_in[3] att_src, d_in[4] att_dst cancel (segment softmax sums to 1)
    const float* bias = (const float*)d_in[5];
    const float* W1   = (const float*)d_in[6];
    const float* b1   = (const float*)d_in[7];
    const float* W2   = (const float*)d_in[8];
    const float* b2   = (const float*)d_in[9];
    float* out = (float*)d_out;

    const int N = in_sizes[0] / D;
    const int E = in_sizes[1] / 2;

    char* ws = (char*)d_ws;
    int* flag = (int*)ws;
    const size_t off = (((size_t)N * 4) + 255) & ~(size_t)255;
    unsigned short* packAW  = (unsigned short*)(ws + off);            // 8192 B
    unsigned short* packAW1 = (unsigned short*)(ws + off + 8192);     // 4096 B
    float*          packBias= (float*)(ws + off + 12288);             // 4096 B
    float*          packB1  = (float*)(ws + off + 16384);             // 2048 B
    float*          packW2  = (float*)(ws + off + 18432);             // 2048 B

    prep_kernel<<<256, 256, 0, stream>>>(Wlin, W1, bias, b1, W2, flag,
                                         packAW, packAW1, packBias, packB1, packW2, N);
    edge_flag_kernel<<<(E / 4 + 256) / 256, 256, 0, stream>>>(eidx, flag, E);
    gat_mfma2<<<(N + 127) / 128, 256, 0, stream>>>(x, flag, packAW, packAW1,
                                                   packBias, packB1, packW2, b2, out, N);
}